// Round 10
// baseline (179.880 us; speedup 1.0000x reference)
//
#include <hip/hip_runtime.h>
#include <hip/hip_fp16.h>

// Problem constants (from reference setup_inputs)
#define N_TF    1024
#define N_GENES 20000
#define WW      4
#define FANIN   16
#define BATCH   128
#define EPG     (WW * FANIN)            // 64 edges per gene
#define MM      (N_GENES * WW)          // 80000 nodes
#define NNZ1    (N_GENES * EPG)

// fused geometry: 1 gene per wave, 16 waves (1024 thr) per block
#define GPB      16
#define NTHREADS 1024
#define NBLK     (N_GENES / GPB)        // 1250
#define YROW     132                    // yt row stride (floats): 16B-aligned,
                                        // bank rotation 132%32=4

typedef unsigned int uint32;

// ---------------------------------------------------------------------------
// Batched fast tanh for 2 values: 2x exp + ONE rcp (exact identity, fp32).
__device__ __forceinline__ float2 fast_tanh2(float a, float b) {
    const float ta = __expf(2.0f * a);
    const float tb = __expf(2.0f * b);
    const float da = ta + 1.0f;
    const float db = tb + 1.0f;
    const float r  = __builtin_amdgcn_rcpf(da * db);
    return make_float2(fmaf(-2.0f * db, r, 1.0f),
                       fmaf(-2.0f * da, r, 1.0f));
}

__device__ __forceinline__ float cvt_ub0(uint32 v) {
#if __has_builtin(__builtin_amdgcn_cvt_f32_ubyte0)
    return __builtin_amdgcn_cvt_f32_ubyte0(v);
#else
    return (float)(v & 0xffu);
#endif
}
__device__ __forceinline__ float cvt_ub1(uint32 v) {
#if __has_builtin(__builtin_amdgcn_cvt_f32_ubyte1)
    return __builtin_amdgcn_cvt_f32_ubyte1(v);
#else
    return (float)((v >> 8) & 0xffu);
#endif
}
__device__ __forceinline__ float cvt_ub2(uint32 v) {
#if __has_builtin(__builtin_amdgcn_cvt_f32_ubyte2)
    return __builtin_amdgcn_cvt_f32_ubyte2(v);
#else
    return (float)((v >> 16) & 0xffu);
#endif
}
__device__ __forceinline__ float cvt_ub3(uint32 v) {
#if __has_builtin(__builtin_amdgcn_cvt_f32_ubyte3)
    return __builtin_amdgcn_cvt_f32_ubyte3(v);
#else
    return (float)((v >> 24) & 0xffu);
#endif
}

// ---------------------------------------------------------------------------
// prep1: one WAVE per TF row. Exact per-row [min,max] over 128 batch values,
// quantize x = s*u + o (u in [0,255]); xu rows are 128 B coalesced.
__global__ __launch_bounds__(512) void prep1_kernel(
    const float* __restrict__ features,      // [B][N_TF]
    unsigned char* __restrict__ xu,          // [N_TF][B]
    float2*       __restrict__ so)           // [N_TF] (scale, offset)
{
    const int wid  = threadIdx.x >> 6;       // 0..7
    const int lane = threadIdx.x & 63;
    const int tf   = blockIdx.x * 8 + wid;   // grid 128 -> 1024 rows

    const float a = features[(2 * lane)     * N_TF + tf];
    const float b = features[(2 * lane + 1) * N_TF + tf];
    float mn = fminf(a, b), mx = fmaxf(a, b);
#pragma unroll
    for (int off = 1; off < 64; off <<= 1) {
        mn = fminf(mn, __shfl_xor(mn, off, 64));
        mx = fmaxf(mx, __shfl_xor(mx, off, 64));
    }
    const float range = fmaxf(mx - mn, 1e-20f);
    const float inv   = 255.0f / range;
    const float s     = range * (1.0f / 255.0f);

    float va = fmaf(a - mn, inv, 0.5f);      // round-to-nearest via +0.5,trunc
    float vb = fmaf(b - mn, inv, 0.5f);
    va = fminf(fmaxf(va, 0.0f), 255.0f);
    vb = fminf(fmaxf(vb, 0.0f), 255.0f);
    const uint32 ua = (uint32)va;
    const uint32 ub = (uint32)vb;
    *(unsigned short*)(xu + tf * BATCH + 2 * lane) =
        (unsigned short)(ua | (ub << 8));

    if (lane == 0) so[tf] = make_float2(s, mn);
}

// ---------------------------------------------------------------------------
// prep2: one thread per node. Folds per-row quant algebra into weights/bias:
//   z = sum_j (w_j s_rj) u_rj + (b1 + sum_j w_j o_rj)
__global__ __launch_bounds__(256) void prep2_kernel(
    const int*    __restrict__ in1,
    const float*  __restrict__ w1,
    const float*  __restrict__ b1,
    const float2* __restrict__ so,
    float*        __restrict__ w1s,
    float*        __restrict__ b1p)
{
    const int n = blockIdx.x * 256 + threadIdx.x;
    if (n >= MM) return;
    float corr = 0.0f;
#pragma unroll
    for (int j = 0; j < FANIN; ++j) {
        const int    e   = n * FANIN + j;
        const int    idx = in1[e];
        const float  w   = w1[e];
        const float2 p   = so[idx];
        w1s[e] = w * p.x;
        corr  = fmaf(w, p.y, corr);
    }
    b1p[n] = b1[n] + corr;
}

// ---------------------------------------------------------------------------
// Fused 3-layer kernel — PAIR-PACKED u8 gathers:
//  One global_load_dword serves TWO edges: lanes 0-31 read edge A's 128 B row
//  (dword = 4 batch u8 each), lanes 32-63 edge B's. 32 gather instrs/gene
//  (was 64) -> halves the per-instruction L1/TA wall.
//  Edge offsets/weights staged wave-uniform via s_load_dwordx4; per pair:
//  v_cndmask row-select + v_add lane offset. fp32 accumulation; even/odd
//  partial sums merged with shfl_xor(32) before tanh.
__global__ __launch_bounds__(NTHREADS, 4) void fused_kernel(
    const unsigned char* __restrict__ xu,   // [N_TF][128] u8
    const int*    __restrict__ in1,    // [NNZ1]
    const float*  __restrict__ w1s,    // [NNZ1]  (= w1 * s_row)
    const float*  __restrict__ b1p,    // [M]     (= b1 + sum w1*o_row)
    const float*  __restrict__ w2,     // [M*W]
    const float*  __restrict__ b2,     // [M]
    const float*  __restrict__ w3,     // [N_GENES*W]
    const float*  __restrict__ b3,     // [N_GENES]
    float*        __restrict__ out)    // [B][N_GENES]
{
    __shared__ float yt[GPB * YROW];   // 16*132*4 = 8448 B

    const int tid  = threadIdx.x;
    const int wid  = __builtin_amdgcn_readfirstlane(tid >> 6);   // uniform
    const int lane = tid & 63;
    const int g    = blockIdx.x * GPB + wid;                     // uniform
    const bool odd = (lane & 32) != 0;     // which edge of the pair
    const uint32 lb = (uint32)((lane & 31) << 2);  // dword slot within row

    const uint4*  __restrict__ ig = (const uint4*)(in1 + g * EPG);  // 16 x uint4
    const float4* __restrict__ wg = (const float4*)(w1s + g * EPG); // 16 x float4

    float4 acc[WW];
#pragma unroll
    for (int i = 0; i < WW; ++i) acc[i] = make_float4(0.f, 0.f, 0.f, 0.f);

#pragma unroll
    for (int half = 0; half < 2; ++half) {
        // ---- uniform (SGPR) staging: 32 indices + 32 weights ---------------
        uint32 idx[32];
        float  wsc[32];
#pragma unroll
        for (int k = 0; k < 8; ++k) {
            const uint4  iq = ig[half * 8 + k];      // s_load_dwordx4
            const float4 wq = wg[half * 8 + k];      // s_load_dwordx4
            idx[k * 4 + 0] = iq.x;  idx[k * 4 + 1] = iq.y;
            idx[k * 4 + 2] = iq.z;  idx[k * 4 + 3] = iq.w;
            wsc[k * 4 + 0] = wq.x;  wsc[k * 4 + 1] = wq.y;
            wsc[k * 4 + 2] = wq.z;  wsc[k * 4 + 3] = wq.w;
        }
        // ---- issue 16 pair-loads (2 edges each, 16-deep in flight) ---------
        uint32 xv[16];
#pragma unroll
        for (int p = 0; p < 16; ++p) {
            const uint32 offA = idx[2 * p]     << 7;   // row byte offset (SALU)
            const uint32 offB = idx[2 * p + 1] << 7;
            const uint32 off  = (odd ? offB : offA) + lb;   // cndmask + add
            xv[p] = *(const uint32*)(xu + off);    // global_load_dword saddr+v
        }
        // ---- consume: 4 batch elems per lane, fp32 acc ---------------------
#pragma unroll
        for (int p = 0; p < 16; ++p) {
            const float  w  = odd ? wsc[2 * p + 1] : wsc[2 * p];  // cndmask
            const uint32 v  = xv[p];
            const int    nd = (half * 32 + 2 * p) >> 4;   // node (uniform)
            acc[nd].x = fmaf(w, cvt_ub0(v), acc[nd].x);
            acc[nd].y = fmaf(w, cvt_ub1(v), acc[nd].y);
            acc[nd].z = fmaf(w, cvt_ub2(v), acc[nd].z);
            acc[nd].w = fmaf(w, cvt_ub3(v), acc[nd].w);
        }
    }

    // ---- merge even/odd half-wave partial sums (both halves get total) -----
#pragma unroll
    for (int i = 0; i < WW; ++i) {
        acc[i].x += __shfl_xor(acc[i].x, 32, 64);
        acc[i].y += __shfl_xor(acc[i].y, 32, 64);
        acc[i].z += __shfl_xor(acc[i].z, 32, 64);
        acc[i].w += __shfl_xor(acc[i].w, 32, 64);
    }

    float4 h1[WW];
#pragma unroll
    for (int i = 0; i < WW; ++i) {
        const float bb = b1p[g * WW + i];                            // s_load
        const float2 t0 = fast_tanh2(acc[i].x + bb, acc[i].y + bb);
        const float2 t1 = fast_tanh2(acc[i].z + bb, acc[i].w + bb);
        h1[i] = make_float4(t0.x, t0.y, t1.x, t1.y);
    }

    // ---- Layer 2: dense 4x4 (weights via s_load) ---------------------------
    float4 h2[WW];
#pragma unroll
    for (int i = 0; i < WW; ++i) {
        const float4 w  = *(const float4*)(w2 + g * 16 + i * 4);     // s_load
        const float  bb = b2[g * WW + i];
        const float s0 = bb + w.x * h1[0].x + w.y * h1[1].x
                            + w.z * h1[2].x + w.w * h1[3].x;
        const float s1 = bb + w.x * h1[0].y + w.y * h1[1].y
                            + w.z * h1[2].y + w.w * h1[3].y;
        const float s2 = bb + w.x * h1[0].z + w.y * h1[1].z
                            + w.z * h1[2].z + w.w * h1[3].z;
        const float s3 = bb + w.x * h1[0].w + w.y * h1[1].w
                            + w.z * h1[2].w + w.w * h1[3].w;
        const float2 t0 = fast_tanh2(s0, s1);
        const float2 t1 = fast_tanh2(s2, s3);
        h2[i] = make_float4(t0.x, t0.y, t1.x, t1.y);
    }

    // ---- Layer 3: sum 4 nodes ----------------------------------------------
    const float4 wv3 = *(const float4*)(w3 + g * 4);                 // s_load
    const float  bv  = b3[g];
    float4 y;
    y.x = bv + wv3.x * h2[0].x + wv3.y * h2[1].x + wv3.z * h2[2].x + wv3.w * h2[3].x;
    y.y = bv + wv3.x * h2[0].y + wv3.y * h2[1].y + wv3.z * h2[2].y + wv3.w * h2[3].y;
    y.z = bv + wv3.x * h2[0].z + wv3.y * h2[1].z + wv3.z * h2[2].z + wv3.w * h2[3].z;
    y.w = bv + wv3.x * h2[0].w + wv3.y * h2[1].w + wv3.z * h2[2].w + wv3.w * h2[3].w;

    // ---- stash to LDS [gene][batch] (lanes 0-31; halves hold identical y) --
    if (!odd)
        *(float4*)(yt + wid * YROW + ((lane & 31) << 2)) = y;  // ds_write_b128

    __syncthreads();

    // ---- coalesced store: 16 consecutive genes per batch row (64 B runs) ---
    const int g0 = blockIdx.x * GPB;
#pragma unroll
    for (int it = 0; it < (BATCH * GPB) / NTHREADS; ++it) {          // 2
        const int idx = it * NTHREADS + tid;
        const int gq  = idx & (GPB - 1);
        const int b   = idx >> 4;
        out[b * N_GENES + g0 + gq] = yt[gq * YROW + b];
    }
}

// ---------------------------------------------------------------------------
extern "C" void kernel_launch(void* const* d_in, const int* in_sizes, int n_in,
                              void* d_out, int out_size, void* d_ws, size_t ws_size,
                              hipStream_t stream)
{
    // order: features, w1, b1, w2, b2, w3, b3, out1, in1, out2, in2, out3, in3
    const float* features = (const float*)d_in[0];
    const float* w1 = (const float*)d_in[1];
    const float* b1 = (const float*)d_in[2];
    const float* w2 = (const float*)d_in[3];
    const float* b2 = (const float*)d_in[4];
    const float* w3 = (const float*)d_in[5];
    const float* b3 = (const float*)d_in[6];
    const int*   in1 = (const int*)d_in[8];
    float* out = (float*)d_out;

    // ws layout: [xu 128 KiB][so 8 KiB][w1s 5 MiB][b1p 320 KB]
    unsigned char* xu  = (unsigned char*)d_ws;
    float2*        so  = (float2*)((char*)d_ws + (size_t)N_TF * BATCH);
    float*         w1s = (float*)((char*)so + (size_t)N_TF * sizeof(float2));
    float*         b1p = w1s + NNZ1;

    hipLaunchKernelGGL(prep1_kernel, dim3(N_TF / 8), dim3(512), 0, stream,
                       features, xu, so);
    hipLaunchKernelGGL(prep2_kernel, dim3((MM + 255) / 256), dim3(256), 0, stream,
                       in1, w1, b1, so, w1s, b1p);
    hipLaunchKernelGGL(fused_kernel, dim3(NBLK), dim3(NTHREADS), 0, stream,
                       xu, in1, w1s, b1p, w2, b2, w3, b3, out);
}

// Round 11
// 117.697 us; speedup vs baseline: 1.5283x; 1.5283x over previous
//
#include <hip/hip_runtime.h>
#include <hip/hip_fp16.h>

// Problem constants (from reference setup_inputs)
#define N_TF    1024
#define N_GENES 20000
#define WW      4
#define FANIN   16
#define BATCH   128
#define EPG     (WW * FANIN)            // 64 edges per gene
#define MM      (N_GENES * WW)          // 80000 nodes
#define NNZ1    (N_GENES * EPG)

// fused geometry: 1 gene per wave, 16 waves (1024 thr) per block
#define GPB      16
#define NTHREADS 1024
#define NBLK     (N_GENES / GPB)        // 1250
#define YROW     (BATCH + 2)            // yt row stride (floats)

typedef unsigned int uint32;

// ---------------------------------------------------------------------------
// Batched fast tanh for 2 values: 2x exp + ONE rcp (exact identity, fp32).
__device__ __forceinline__ float2 fast_tanh2(float a, float b) {
    const float ta = __expf(2.0f * a);
    const float tb = __expf(2.0f * b);
    const float da = ta + 1.0f;
    const float db = tb + 1.0f;
    const float r  = __builtin_amdgcn_rcpf(da * db);
    return make_float2(fmaf(-2.0f * db, r, 1.0f),
                       fmaf(-2.0f * da, r, 1.0f));
}

__device__ __forceinline__ float cvt_ub0(uint32 v) {
#if __has_builtin(__builtin_amdgcn_cvt_f32_ubyte0)
    return __builtin_amdgcn_cvt_f32_ubyte0(v);
#else
    return (float)(v & 0xffu);
#endif
}
__device__ __forceinline__ float cvt_ub1(uint32 v) {
#if __has_builtin(__builtin_amdgcn_cvt_f32_ubyte1)
    return __builtin_amdgcn_cvt_f32_ubyte1(v);
#else
    return (float)((v >> 8) & 0xffu);
#endif
}

// ---------------------------------------------------------------------------
// prep1: one WAVE per TF row. Exact per-row [min,max] over 128 batch values,
// quantize x = s*u + o (u in [0,255]); xu rows are 128 B coalesced.
__global__ __launch_bounds__(512) void prep1_kernel(
    const float* __restrict__ features,      // [B][N_TF]
    unsigned char* __restrict__ xu,          // [N_TF][B]
    float2*       __restrict__ so)           // [N_TF] (scale, offset)
{
    const int wid  = threadIdx.x >> 6;       // 0..7
    const int lane = threadIdx.x & 63;
    const int tf   = blockIdx.x * 8 + wid;   // grid 128 -> 1024 rows

    const float a = features[(2 * lane)     * N_TF + tf];
    const float b = features[(2 * lane + 1) * N_TF + tf];
    float mn = fminf(a, b), mx = fmaxf(a, b);
#pragma unroll
    for (int off = 1; off < 64; off <<= 1) {
        mn = fminf(mn, __shfl_xor(mn, off, 64));
        mx = fmaxf(mx, __shfl_xor(mx, off, 64));
    }
    const float range = fmaxf(mx - mn, 1e-20f);
    const float inv   = 255.0f / range;
    const float s     = range * (1.0f / 255.0f);

    float va = fmaf(a - mn, inv, 0.5f);      // round-to-nearest via +0.5,trunc
    float vb = fmaf(b - mn, inv, 0.5f);
    va = fminf(fmaxf(va, 0.0f), 255.0f);
    vb = fminf(fmaxf(vb, 0.0f), 255.0f);
    const uint32 ua = (uint32)va;
    const uint32 ub = (uint32)vb;
    *(unsigned short*)(xu + tf * BATCH + 2 * lane) =
        (unsigned short)(ua | (ub << 8));

    if (lane == 0) so[tf] = make_float2(s, mn);
}

// ---------------------------------------------------------------------------
// prep2: one thread per node. Folds per-row quant algebra into weights/bias:
//   z = sum_j (w_j s_rj) u_rj + (b1 + sum_j w_j o_rj)
__global__ __launch_bounds__(256) void prep2_kernel(
    const int*    __restrict__ in1,
    const float*  __restrict__ w1,
    const float*  __restrict__ b1,
    const float2* __restrict__ so,
    float*        __restrict__ w1s,
    float*        __restrict__ b1p)
{
    const int n = blockIdx.x * 256 + threadIdx.x;
    if (n >= MM) return;
    float corr = 0.0f;
#pragma unroll
    for (int j = 0; j < FANIN; ++j) {
        const int    e   = n * FANIN + j;
        const int    idx = in1[e];
        const float  w   = w1[e];
        const float2 p   = so[idx];
        w1s[e] = w * p.x;
        corr  = fmaf(w, p.y, corr);
    }
    b1p[n] = b1[n] + corr;
}

// ---------------------------------------------------------------------------
// Fused 3-layer kernel — round-9 structure, REGISTER CAP FIXED.
// __launch_bounds__(1024, 1): 1 block/CU -> 4 waves/EU -> 128-VGPR budget.
// (Rounds 4/6/9 ran at a 32-VGPR cap from launch_bounds' 2nd arg acting as
// min-blocks/CU: round-4 (512,8) measured VGPR=32, round-10 (1024,4)
// spilled to scratch at VGPR=28, WRITE_SIZE 310 MB. With 128 VGPRs the
// 32-deep gather batch actually stays in flight.)
__global__ __launch_bounds__(NTHREADS, 1) void fused_kernel(
    const unsigned char* __restrict__ xu,   // [N_TF][128] u8
    const int*    __restrict__ in1,    // [NNZ1]
    const float*  __restrict__ w1s,    // [NNZ1]  (= w1 * s_row)
    const float*  __restrict__ b1p,    // [M]     (= b1 + sum w1*o_row)
    const float*  __restrict__ w2,     // [M*W]
    const float*  __restrict__ b2,     // [M]
    const float*  __restrict__ w3,     // [N_GENES*W]
    const float*  __restrict__ b3,     // [N_GENES]
    float*        __restrict__ out)    // [B][N_GENES]
{
    __shared__ float yt[GPB * YROW];   // 16*130*4 = 8320 B

    const int tid  = threadIdx.x;
    const int wid  = __builtin_amdgcn_readfirstlane(tid >> 6);   // uniform
    const int lane = tid & 63;
    const int g    = blockIdx.x * GPB + wid;                     // uniform
    const int voff = lane << 1;        // byte offset of this lane's u8-pair
    const char* xb = (const char*)xu;

    const uint4*  __restrict__ ig = (const uint4*)(in1 + g * EPG);  // 16 x uint4
    const float4* __restrict__ wg = (const float4*)(w1s + g * EPG); // 16 x float4

    float2 acc[WW];
#pragma unroll
    for (int i = 0; i < WW; ++i) acc[i] = make_float2(0.0f, 0.0f);

#pragma unroll
    for (int half = 0; half < 2; ++half) {
        // ---- uniform (SGPR) loads: 32 indices + 32 weights -----------------
        uint32 idx[32];
        float  wsc[32];
#pragma unroll
        for (int k = 0; k < 8; ++k) {
            const uint4  iq = ig[half * 8 + k];      // s_load_dwordx4
            const float4 wq = wg[half * 8 + k];      // s_load_dwordx4
            idx[k * 4 + 0] = iq.x;  idx[k * 4 + 1] = iq.y;
            idx[k * 4 + 2] = iq.z;  idx[k * 4 + 3] = iq.w;
            wsc[k * 4 + 0] = wq.x;  wsc[k * 4 + 1] = wq.y;
            wsc[k * 4 + 2] = wq.z;  wsc[k * 4 + 3] = wq.w;
        }
        // ---- issue 32 gathers (genuinely 32-deep in flight now) ------------
        unsigned short xv[32];
#pragma unroll
        for (int t = 0; t < 32; ++t)
            xv[t] = *(const unsigned short*)(xb + (((size_t)idx[t]) << 7) + voff);
        // ---- consume: 2 cvt + 2 fma per edge, fp32 accumulation ------------
#pragma unroll
        for (int t = 0; t < 32; ++t) {
            const uint32 v  = (uint32)xv[t];
            const float  x0 = cvt_ub0(v);
            const float  x1 = cvt_ub1(v);
            const int tt = half * 32 + t;
            const int nd = tt >> 4;                   // node (layout node-major)
            acc[nd].x = fmaf(wsc[t], x0, acc[nd].x);  // v_fmac, SGPR src0
            acc[nd].y = fmaf(wsc[t], x1, acc[nd].y);
        }
    }

    float2 h1[WW];
#pragma unroll
    for (int i = 0; i < WW; ++i) {
        const float bb = b1p[g * WW + i];                            // s_load
        h1[i] = fast_tanh2(acc[i].x + bb, acc[i].y + bb);
    }

    // ---- Layer 2: dense 4x4 (weights via s_load) ---------------------------
    float2 h2[WW];
#pragma unroll
    for (int i = 0; i < WW; ++i) {
        const float4 w  = *(const float4*)(w2 + g * 16 + i * 4);     // s_load
        const float  bb = b2[g * WW + i];
        const float sx = bb + w.x * h1[0].x + w.y * h1[1].x
                            + w.z * h1[2].x + w.w * h1[3].x;
        const float sy = bb + w.x * h1[0].y + w.y * h1[1].y
                            + w.z * h1[2].y + w.w * h1[3].y;
        h2[i] = fast_tanh2(sx, sy);
    }

    // ---- Layer 3: sum 4 nodes ----------------------------------------------
    const float4 wv3 = *(const float4*)(w3 + g * 4);                 // s_load
    const float  bv  = b3[g];
    const float yx = bv + wv3.x * h2[0].x + wv3.y * h2[1].x
                        + wv3.z * h2[2].x + wv3.w * h2[3].x;
    const float yy = bv + wv3.x * h2[0].y + wv3.y * h2[1].y
                        + wv3.z * h2[2].y + wv3.w * h2[3].y;

    // ---- stash to LDS [gene][batch] ----------------------------------------
    float2* ytw = (float2*)(yt + wid * YROW);
    ytw[lane] = make_float2(yx, yy);

    __syncthreads();

    // ---- coalesced store: 16 consecutive genes per batch row (64 B runs) ---
    const int g0 = blockIdx.x * GPB;
#pragma unroll
    for (int it = 0; it < (BATCH * GPB) / NTHREADS; ++it) {          // 2
        const int idx = it * NTHREADS + tid;
        const int gq  = idx & (GPB - 1);
        const int b   = idx >> 4;
        out[b * N_GENES + g0 + gq] = yt[gq * YROW + b];
    }
}

// ---------------------------------------------------------------------------
extern "C" void kernel_launch(void* const* d_in, const int* in_sizes, int n_in,
                              void* d_out, int out_size, void* d_ws, size_t ws_size,
                              hipStream_t stream)
{
    // order: features, w1, b1, w2, b2, w3, b3, out1, in1, out2, in2, out3, in3
    const float* features = (const float*)d_in[0];
    const float* w1 = (const float*)d_in[1];
    const float* b1 = (const float*)d_in[2];
    const float* w2 = (const float*)d_in[3];
    const float* b2 = (const float*)d_in[4];
    const float* w3 = (const float*)d_in[5];
    const float* b3 = (const float*)d_in[6];
    const int*   in1 = (const int*)d_in[8];
    float* out = (float*)d_out;

    // ws layout: [xu 128 KiB][so 8 KiB][w1s 5 MiB][b1p 320 KB]
    unsigned char* xu  = (unsigned char*)d_ws;
    float2*        so  = (float2*)((char*)d_ws + (size_t)N_TF * BATCH);
    float*         w1s = (float*)((char*)so + (size_t)N_TF * sizeof(float2));
    float*         b1p = w1s + NNZ1;

    hipLaunchKernelGGL(prep1_kernel, dim3(N_TF / 8), dim3(512), 0, stream,
                       features, xu, so);
    hipLaunchKernelGGL(prep2_kernel, dim3((MM + 255) / 256), dim3(256), 0, stream,
                       in1, w1, b1, so, w1s, b1p);
    hipLaunchKernelGGL(fused_kernel, dim3(NBLK), dim3(NTHREADS), 0, stream,
                       xu, in1, w1s, b1p, w2, b2, w3, b3, out);
}